// Round 7
// baseline (233.121 us; speedup 1.0000x reference)
//
#include <hip/hip_runtime.h>
#include <hip/hip_bf16.h>

#define NODES 256

typedef float f32x4 __attribute__((ext_vector_type(4)));

// ---------------------------------------------------------------------------
// Prologue (1 block): Akima node slopes per the reference recurrence, packed
// as per-interval float4 tab[i] = {v[i], v[i+1], h*s[i], h*s[i+1]} into d_ws.
// (h pre-folded into the slope terms: saves 2 VALU/elem in the main loop;
//  differs from ref only in mult association, <=1 ulp.)
// ---------------------------------------------------------------------------
__global__ __launch_bounds__(256) void akima_prologue(
    const float* __restrict__ value, float4* __restrict__ tab) {
  __shared__ float me[NODES + 3];
  __shared__ float s[NODES];
  const int t = threadIdx.x;
  const float h = 1.0f / 255.0f;

  if (t < NODES - 1) me[t + 2] = (value[t + 1] - value[t]) / h;
  __syncthreads();
  if (t == 0) {
    float m0 = me[2], m1 = me[3];
    float m_m1 = 2.0f * m0 - m1;
    me[1] = m_m1;
    me[0] = 2.0f * m_m1 - m0;
    float mL = me[NODES], mL1 = me[NODES - 1];
    float m_p1 = 2.0f * mL - mL1;
    me[NODES + 1] = m_p1;
    me[NODES + 2] = 2.0f * m_p1 - mL;
  }
  __syncthreads();
  {
    float w1 = fabsf(me[t + 3] - me[t + 2]);
    float w2 = fabsf(me[t + 1] - me[t]);
    float denom = w1 + w2;
    s[t] = (denom > 0.0f) ? (w1 * me[t + 1] + w2 * me[t + 2]) / denom
                          : 0.5f * (me[t + 1] + me[t + 2]);
  }
  __syncthreads();
  if (t < NODES - 1)
    tab[t] = make_float4(value[t], value[t + 1], h * s[t], h * s[t + 1]);
}

// ---------------------------------------------------------------------------
// Hermite eval with pre-scaled slopes. tt >= 0 so floor == int-trunc and the
// lower idx clamp is dead.
// ---------------------------------------------------------------------------
__device__ __forceinline__ float akima_herm(float x, const float4& c) {
  float tt = fminf(fmaxf(x, 0.0f), 1.0f) * 255.0f;
  int idx = min((int)tt, NODES - 2);
  float u = tt - (float)idx;
  float u2 = u * u;
  float u3 = u2 * u;
  float h00 = 2.0f * u3 - 3.0f * u2 + 1.0f;
  float h10 = u3 - 2.0f * u2 + u;
  float h01 = -2.0f * u3 + 3.0f * u2;
  float h11 = u3 - u2;
  return h00 * c.x + h10 * c.z + h01 * c.y + h11 * c.w;
}

__device__ __forceinline__ int akima_idx(float x) {
  float tt = fminf(fmaxf(x, 0.0f), 1.0f) * 255.0f;
  return min((int)tt, NODES - 2);
}

// ---------------------------------------------------------------------------
// Main. Unroll x4: issue 4 independent grid-strided float4 loads up front
// (MLP 1 -> 4 per wave), then eval, then 4 stores. Table gathers split
// across DS (LDS) and TA/L1 (global, 4 KB resident) pipes; streaming
// traffic is nontemporal so it doesn't evict the table.
// ---------------------------------------------------------------------------
__global__ __launch_bounds__(256) void akima_main(
    const float* __restrict__ in, const float4* __restrict__ gtab,
    float* __restrict__ out, long long n, long long n4) {
  __shared__ float4 stab[NODES - 1];
  if (threadIdx.x < NODES - 1) stab[threadIdx.x] = gtab[threadIdx.x];
  __syncthreads();

  const f32x4* __restrict__ in4 = reinterpret_cast<const f32x4*>(in);
  f32x4* __restrict__ out4 = reinterpret_cast<f32x4*>(out);
  const long long T = (long long)gridDim.x * blockDim.x;  // total threads
  const long long i0 = (long long)blockIdx.x * blockDim.x + threadIdx.x;

  long long i = i0;
  // fast path: 4 float4s per thread per outer iteration
  for (; i + 3 * T < n4; i += 4 * T) {
    f32x4 xv[4], rv[4];
#pragma unroll
    for (int k = 0; k < 4; ++k)
      xv[k] = __builtin_nontemporal_load(&in4[i + k * T]);
#pragma unroll
    for (int k = 0; k < 4; ++k) {
      f32x4 x4 = xv[k];
      int ia = akima_idx(x4.x);
      int ib = akima_idx(x4.y);
      int ic = akima_idx(x4.z);
      int id = akima_idx(x4.w);
      float4 ca = stab[ia];  // DS pipe
      float4 cb = gtab[ib];  // TA/L1 pipe
      float4 cc = stab[ic];  // DS pipe
      float4 cd = gtab[id];  // TA/L1 pipe
      f32x4 r;
      r.x = akima_herm(x4.x, ca);
      r.y = akima_herm(x4.y, cb);
      r.z = akima_herm(x4.z, cc);
      r.w = akima_herm(x4.w, cd);
      rv[k] = r;
    }
#pragma unroll
    for (int k = 0; k < 4; ++k)
      __builtin_nontemporal_store(rv[k], &out4[i + k * T]);
  }
  // remainder float4s
  for (; i < n4; i += T) {
    f32x4 x4 = __builtin_nontemporal_load(&in4[i]);
    f32x4 r;
    r.x = akima_herm(x4.x, stab[akima_idx(x4.x)]);
    r.y = akima_herm(x4.y, gtab[akima_idx(x4.y)]);
    r.z = akima_herm(x4.z, stab[akima_idx(x4.z)]);
    r.w = akima_herm(x4.w, gtab[akima_idx(x4.w)]);
    __builtin_nontemporal_store(r, &out4[i]);
  }
  // scalar tail (n % 4) — no-op at the bench shape
  for (long long j = n4 * 4 + i0; j < n; j += T) {
    float x = in[j];
    out[j] = akima_herm(x, stab[akima_idx(x)]);
  }
}

extern "C" void kernel_launch(void* const* d_in, const int* in_sizes, int n_in,
                              void* d_out, int out_size, void* d_ws, size_t ws_size,
                              hipStream_t stream) {
  const float* in = (const float*)d_in[0];     // (32,1024,1024) f32
  const float* value = (const float*)d_in[1];  // (256,) f32
  float* out = (float*)d_out;
  float4* tab = (float4*)d_ws;                 // 255 * 16 B = 4080 B scratch

  long long n = (long long)in_sizes[0];
  long long n4 = n / 4;

  akima_prologue<<<1, 256, 0, stream>>>(value, tab);

  long long want = (n4 + 255) / 256;
  int blocks = (int)(want < 2048 ? (want > 0 ? want : 1) : 2048);
  akima_main<<<blocks, 256, 0, stream>>>(in, tab, out, n, n4);
}

// Round 10
// 229.937 us; speedup vs baseline: 1.0139x; 1.0139x over previous
//
#include <hip/hip_runtime.h>
#include <hip/hip_bf16.h>

#define NODES 256

typedef float f32x4 __attribute__((ext_vector_type(4)));

// ---------------------------------------------------------------------------
// Prologue (1 block): Akima node slopes per the reference recurrence, then
// per-interval CUBIC coefficients tab[i] = {a,b,c,d} with
//   p(u) = a + u*(b + u*(c + u*d)),   u in [0,1]
//   a = v0, b = h*s0, c = 3(v1-v0) - 2h*s0 - h*s1, d = 2(v0-v1) + h*s0 + h*s1
// Same polynomial as the reference Hermite form (few-ulp difference).
// ---------------------------------------------------------------------------
__global__ __launch_bounds__(256) void akima_prologue(
    const float* __restrict__ value, f32x4* __restrict__ tab) {
  __shared__ float me[NODES + 3];
  __shared__ float s[NODES];
  const int t = threadIdx.x;
  const float h = 1.0f / 255.0f;

  if (t < NODES - 1) me[t + 2] = (value[t + 1] - value[t]) / h;
  __syncthreads();
  if (t == 0) {
    float m0 = me[2], m1 = me[3];
    float m_m1 = 2.0f * m0 - m1;
    me[1] = m_m1;
    me[0] = 2.0f * m_m1 - m0;
    float mL = me[NODES], mL1 = me[NODES - 1];
    float m_p1 = 2.0f * mL - mL1;
    me[NODES + 1] = m_p1;
    me[NODES + 2] = 2.0f * m_p1 - mL;
  }
  __syncthreads();
  {
    float w1 = fabsf(me[t + 3] - me[t + 2]);
    float w2 = fabsf(me[t + 1] - me[t]);
    float denom = w1 + w2;
    s[t] = (denom > 0.0f) ? (w1 * me[t + 1] + w2 * me[t + 2]) / denom
                          : 0.5f * (me[t + 1] + me[t + 2]);
  }
  __syncthreads();
  if (t < NODES - 1) {
    float v0 = value[t], v1 = value[t + 1];
    float hs0 = h * s[t], hs1 = h * s[t + 1];
    f32x4 c;
    c.x = v0;                                   // a
    c.y = hs0;                                  // b
    c.z = 3.0f * (v1 - v0) - 2.0f * hs0 - hs1;  // c
    c.w = 2.0f * (v0 - v1) + hs0 + hs1;         // d
    tab[t] = c;
  }
}

__device__ __forceinline__ float akima_poly(float x, const f32x4& c) {
  float tt = fminf(fmaxf(x, 0.0f), 1.0f) * 255.0f;
  int idx = min((int)tt, NODES - 2);
  float u = tt - (float)idx;
  return c.x + u * (c.y + u * (c.z + u * c.w));  // Horner: 3 FMA
}

__device__ __forceinline__ int akima_idx(float x) {
  float tt = fminf(fmaxf(x, 0.0f), 1.0f) * 255.0f;
  return min((int)tt, NODES - 2);
}

// ---------------------------------------------------------------------------
// Main: flat one-float4-per-thread, copy-like structure. No LDS, no loop.
// Table gathers from global (4 KB, L1-resident); streaming load/store are
// nontemporal (no L1 allocate) so the table is never evicted.
// ---------------------------------------------------------------------------
__global__ __launch_bounds__(256) void akima_main(
    const float* __restrict__ in, const f32x4* __restrict__ gtab,
    float* __restrict__ out, long long n, long long n4) {
  const long long i = (long long)blockIdx.x * blockDim.x + threadIdx.x;
  const f32x4* __restrict__ in4 = reinterpret_cast<const f32x4*>(in);
  f32x4* __restrict__ out4 = reinterpret_cast<f32x4*>(out);

  if (i < n4) {
    f32x4 x4 = __builtin_nontemporal_load(&in4[i]);
    int ia = akima_idx(x4.x);
    int ib = akima_idx(x4.y);
    int ic = akima_idx(x4.z);
    int id = akima_idx(x4.w);
    f32x4 ca = gtab[ia];
    f32x4 cb = gtab[ib];
    f32x4 cc = gtab[ic];
    f32x4 cd = gtab[id];
    f32x4 r;
    r.x = akima_poly(x4.x, ca);
    r.y = akima_poly(x4.y, cb);
    r.z = akima_poly(x4.z, cc);
    r.w = akima_poly(x4.w, cd);
    __builtin_nontemporal_store(r, &out4[i]);
  }

  // scalar tail (n % 4) — handled by the first few threads of block 0;
  // no-op at the bench shape.
  if (blockIdx.x == 0) {
    long long j = n4 * 4 + threadIdx.x;
    if (j < n) {
      float x = in[j];
      out[j] = akima_poly(x, gtab[akima_idx(x)]);
    }
  }
}

extern "C" void kernel_launch(void* const* d_in, const int* in_sizes, int n_in,
                              void* d_out, int out_size, void* d_ws, size_t ws_size,
                              hipStream_t stream) {
  const float* in = (const float*)d_in[0];     // (32,1024,1024) f32
  const float* value = (const float*)d_in[1];  // (256,) f32
  float* out = (float*)d_out;
  f32x4* tab = (f32x4*)d_ws;                   // 255 * 16 B = 4080 B scratch

  long long n = (long long)in_sizes[0];
  long long n4 = n / 4;

  akima_prologue<<<1, 256, 0, stream>>>(value, tab);

  long long blocks = (n4 + 255) / 256;
  if (blocks < 1) blocks = 1;
  akima_main<<<(int)blocks, 256, 0, stream>>>(in, tab, out, n, n4);
}